// Round 1
// baseline (1308.990 us; speedup 1.0000x reference)
//
#include <hip/hip_runtime.h>
#include <stdint.h>

#define TOPK 20
#define BLK 256
#define CAP 2048
#define DELTA 2.0f
#define LSTRIDE 21
#define L2E 1.4426950408889634f
#define IGNORE_INDEX (-100)

typedef float f4v __attribute__((ext_vector_type(4)));

__device__ __forceinline__ unsigned fkey(float x) {
  unsigned b = __float_as_uint(x);
  return (b & 0x80000000u) ? ~b : (b | 0x80000000u);
}
__device__ __forceinline__ float funkey(unsigned k) {
  unsigned b = (k & 0x80000000u) ? (k & 0x7FFFFFFFu) : ~k;
  return __uint_as_float(b);
}

// sorted-descending top-20 insert (fully unrolled, registers only)
__device__ __forceinline__ void ins20(float (&tv)[TOPK], float c) {
  if (c > tv[TOPK - 1]) {
#pragma unroll
    for (int j = 0; j < TOPK; ++j) {
      float hi = fmaxf(tv[j], c);
      c = fminf(tv[j], c);
      tv[j] = hi;
    }
  }
}

// merge two sorted-desc 20-lists (padded to 21 with -inf) -> top-20 into O
__device__ __forceinline__ void merge2(const float* A, const float* B, float* O) {
  int i = 1, j = 1;
  float a = A[0], b = B[0];
#pragma unroll
  for (int k = 0; k < TOPK; ++k) {
    if (a >= b) { O[k] = a; a = A[i]; ++i; }
    else        { O[k] = b; b = B[j]; ++j; }
  }
}

// merge 64 lists living in bufA (stride LSTRIDE, pad slot 20 = -inf).
// ALL 256 threads must call (contains barriers). Returns pointer to result list.
__device__ float* merge64(int tid, float* bufA, float* bufB) {
  float* srcb = bufA;
  float* dstb = bufB;
  for (int s = 32; s >= 1; s >>= 1) {
    __syncthreads();
    if (tid < s) {
      merge2(srcb + tid * LSTRIDE, srcb + (tid + s) * LSTRIDE, dstb + tid * LSTRIDE);
      dstb[tid * LSTRIDE + TOPK] = -INFINITY;
    }
    float* t = srcb; srcb = dstb; dstb = t;
  }
  __syncthreads();
  return srcb;
}

__global__ __launch_bounds__(BLK) void eaft_ce_kernel(
    const float* __restrict__ src, const int* __restrict__ tgt,
    float* __restrict__ acc, int V) {
  __shared__ float s_cand[CAP];
  __shared__ float s_bufA[64 * LSTRIDE];
  __shared__ float s_bufB[64 * LSTRIDE];
  __shared__ float s_wm[4];
  __shared__ float s_wl[4];
  __shared__ unsigned s_maxkey;
  __shared__ int s_cnt;
  __shared__ int s_slow;

  const int tid = threadIdx.x;
  const int row = blockIdx.x;
  if (tid == 0) { s_maxkey = 0u; s_cnt = 0; s_slow = 0; }
  __syncthreads();

  const size_t rowbase = (size_t)row * (size_t)V;
  const float* arow = src + rowbase;
  const int head = (int)((4 - (rowbase & 3)) & 3);
  const f4v* vp = (const f4v*)(arow + head);
  const int nvec = (V - head) >> 2;
  const int tail = V - head - (nvec << 2);

  // ---------- peel: first vec batch + head/tail scalars (prime block max) ----------
  f4v pv = {-INFINITY, -INFINITY, -INFINITY, -INFINITY};
  if (tid < nvec) pv = __builtin_nontemporal_load(vp + tid);
  float ex = -INFINITY;
  if (tid < head) ex = arow[tid];
  else if (tid >= 64 && tid < 64 + tail) ex = arow[head + (nvec << 2) + (tid - 64)];

  float pmax = fmaxf(fmaxf(fmaxf(pv.x, pv.y), fmaxf(pv.z, pv.w)), ex);
  if (pmax > -INFINITY) atomicMax(&s_maxkey, fkey(pmax));
  __syncthreads();  // block max primed with ~1024 samples

  // lane's LSE is referenced to its view `bm` of the block max.
  // exp2 arguments stay small: bm >= max of first ~1024 N(0,1) samples (~3.2s),
  // true max ~4.5s, so exp2((x-bm)*L2E) <= ~e^1.9 -- no overflow for this data.
  float bm = funkey(s_maxkey);
  float lmax = bm;            // lane's known ceiling (avoid redundant atomic posts)
  float cexp = -bm * L2E;
  float l0 = 0.f, l1 = 0.f;   // two independent partial sums (dep-chain split)

  // retroactive pass over peel elements: accumulate LSE + candidate test
  {
    float T = bm - DELTA;
    float vals[5] = {pv.x, pv.y, pv.z, pv.w, ex};
#pragma unroll
    for (int q = 0; q < 5; ++q) {
      float x = vals[q];
      l0 += exp2f(fmaf(x, L2E, cexp));  // exp2(-inf) = 0 for pad lanes
      if (x >= T) {
        int p = atomicAdd(&s_cnt, 1);
        if (p < CAP) s_cand[p] = x;
        if (x > lmax) { lmax = x; atomicMax(&s_maxkey, fkey(x)); }
      }
    }
  }

  // ---------- main streaming loop: 2 nontemporal float4 per thread per iter ----------
  int i = BLK + tid;
  for (; i + BLK < nvec; i += 2 * BLK) {
    f4v a = __builtin_nontemporal_load(vp + i);
    f4v b = __builtin_nontemporal_load(vp + i + BLK);
    float nb = funkey(*(volatile unsigned*)&s_maxkey);
    if (nb > bm) {            // rare: rescale once per iteration, not per element
      float r = exp2f((bm - nb) * L2E);
      l0 *= r; l1 *= r;
      bm = nb; cexp = -bm * L2E;
      if (nb > lmax) lmax = nb;
    }
    float T = bm - DELTA;
    float av[4] = {a.x, a.y, a.z, a.w};
    float bv[4] = {b.x, b.y, b.z, b.w};
#pragma unroll
    for (int q = 0; q < 4; ++q) {
      float x = av[q];
      l0 += exp2f(fmaf(x, L2E, cexp));
      if (x >= T) {           // any new max satisfies x >= T, so max-post nests here
        int p = atomicAdd(&s_cnt, 1);
        if (p < CAP) s_cand[p] = x;
        if (x > lmax) { lmax = x; atomicMax(&s_maxkey, fkey(x)); }
      }
      float y = bv[q];
      l1 += exp2f(fmaf(y, L2E, cexp));
      if (y >= T) {
        int p = atomicAdd(&s_cnt, 1);
        if (p < CAP) s_cand[p] = y;
        if (y > lmax) { lmax = y; atomicMax(&s_maxkey, fkey(y)); }
      }
    }
  }
  if (i < nvec) {  // remainder (at most one float4 per thread)
    f4v a = __builtin_nontemporal_load(vp + i);
    float nb = funkey(*(volatile unsigned*)&s_maxkey);
    if (nb > bm) {
      float r = exp2f((bm - nb) * L2E);
      l0 *= r; l1 *= r;
      bm = nb; cexp = -bm * L2E;
      if (nb > lmax) lmax = nb;
    }
    float T = bm - DELTA;
    float av[4] = {a.x, a.y, a.z, a.w};
#pragma unroll
    for (int q = 0; q < 4; ++q) {
      float x = av[q];
      l0 += exp2f(fmaf(x, L2E, cexp));
      if (x >= T) {
        int p = atomicAdd(&s_cnt, 1);
        if (p < CAP) s_cand[p] = x;
        if (x > lmax) { lmax = x; atomicMax(&s_maxkey, fkey(x)); }
      }
    }
  }

  // ---------- barrier-free wave LSE reduce, then 4-entry cross-wave combine ----------
  {
    float m = bm, l = l0 + l1;  // lanes may hold different bm views -- combine handles it
#pragma unroll
    for (int off = 32; off > 0; off >>= 1) {
      float om = __shfl_down(m, off);
      float ol = __shfl_down(l, off);
      float M = fmaxf(m, om);
      l = l * exp2f((m - M) * L2E) + ol * exp2f((om - M) * L2E);
      m = M;
    }
    if ((tid & 63) == 0) { s_wm[tid >> 6] = m; s_wl[tid >> 6] = l; }
  }
  __syncthreads();  // also makes s_cnt / s_cand / s_maxkey posts visible

  // ---------- top-20 selection from candidates (wave 0 builds 64 lists) ----------
  const int cnt_raw = s_cnt;
  const int C = cnt_raw < CAP ? cnt_raw : CAP;
  if (tid < 64) {
    float tv[TOPK];
#pragma unroll
    for (int j = 0; j < TOPK; ++j) tv[j] = -INFINITY;
    for (int k = tid; k < C; k += 64) ins20(tv, s_cand[k]);
#pragma unroll
    for (int j = 0; j < TOPK; ++j) s_bufA[tid * LSTRIDE + j] = tv[j];
    s_bufA[tid * LSTRIDE + TOPK] = -INFINITY;
  }
  float* R = merge64(tid, s_bufA, s_bufB);

  // ---------- verification vs TRUE row max; rare exact slow path ----------
  const float tmax = funkey(s_maxkey);  // final value: all posts fenced by barriers
  if (tid == 0)
    s_slow = (cnt_raw > CAP || R[TOPK - 1] < tmax - DELTA) ? 1 : 0;
  __syncthreads();

  if (s_slow) {
    float tv[TOPK];
#pragma unroll
    for (int j = 0; j < TOPK; ++j) tv[j] = -INFINITY;
    for (int e = tid; e < V; e += BLK) ins20(tv, arow[e]);
    for (int r = 0; r < 4; ++r) {
      __syncthreads();
      if ((tid >> 6) == r) {
        int lane = tid & 63;
#pragma unroll
        for (int j = 0; j < TOPK; ++j) s_bufA[lane * LSTRIDE + j] = tv[j];
        s_bufA[lane * LSTRIDE + TOPK] = -INFINITY;
      }
      float* Rr = merge64(tid, s_bufA, s_bufB);
      if (tid == 0) {
#pragma unroll
        for (int j = 0; j < TOPK; ++j) s_cand[r * LSTRIDE + j] = Rr[j];
        s_cand[r * LSTRIDE + TOPK] = -INFINITY;
      }
      __syncthreads();
    }
    if (tid == 0) {
      merge2(s_cand + 0 * LSTRIDE, s_cand + 1 * LSTRIDE, s_bufA);
      s_bufA[TOPK] = -INFINITY;
      merge2(s_cand + 2 * LSTRIDE, s_cand + 3 * LSTRIDE, s_bufA + LSTRIDE);
      s_bufA[LSTRIDE + TOPK] = -INFINITY;
      merge2(s_bufA, s_bufA + LSTRIDE, s_bufB);
    }
  }
  __syncthreads();

  // ---------- entropy weight + loss contribution (thread 0) ----------
  if (tid == 0) {
    const float* W = s_slow ? s_bufB : R;
    int t = tgt[row];
    if (t != IGNORE_INDEX) {
      // combine the 4 per-wave LSE partials
      float M = fmaxf(fmaxf(s_wm[0], s_wm[1]), fmaxf(s_wm[2], s_wm[3]));
      float S = 0.f;
#pragma unroll
      for (int k = 0; k < 4; ++k) S += s_wl[k] * exp2f((s_wm[k] - M) * L2E);
      const float lse_row = M + logf(S);

      float tl = arow[t];
      float loss = lse_row - tl;
      float m0 = W[0];
      float S1 = 0.f, Sv = 0.f;
#pragma unroll
      for (int k2 = 0; k2 < TOPK; ++k2) {
        float v = W[k2];
        float e = exp2f((v - m0) * L2E);
        S1 += e;
        Sv += v * e;
      }
      float ent = (m0 + logf(S1)) - Sv / S1;
      float w = ent * (1.0f / 3.0f);
      atomicAdd(&acc[0], w * loss);
      atomicAdd(&acc[1], 1.0f);
    }
  }
}

__global__ void finalize_kernel(const float* __restrict__ acc, float* __restrict__ out) {
  out[0] = acc[0] / acc[1];
}

extern "C" void kernel_launch(void* const* d_in, const int* in_sizes, int n_in,
                              void* d_out, int out_size, void* d_ws, size_t ws_size,
                              hipStream_t stream) {
  const float* src = (const float*)d_in[0];
  const int* tgt = (const int*)d_in[1];
  const int NV = in_sizes[0];
  const int n = in_sizes[1];
  const int V = NV / n;
  float* ws = (float*)d_ws;
  hipMemsetAsync(ws, 0, 2 * sizeof(float), stream);
  eaft_ce_kernel<<<n, BLK, 0, stream>>>(src, tgt, ws, V);
  finalize_kernel<<<1, 1, 0, stream>>>(ws, (float*)d_out);
}